// Round 3
// baseline (81.975 us; speedup 1.0000x reference)
//
#include <hip/hip_runtime.h>

#define G_GEN 65
#define FEAT 8192   // 32*16*16
#define NBASE (G_GEN * FEAT)

typedef float f32x4 __attribute__((ext_vector_type(4)));

// Kernel 1: per-feature stats. f-th thread reads x[g*FEAT + f] for g=0..64
// (coalesced across threads for each g), computes center/radius -> scale, val, cross.
__global__ void feat_stats(const float* __restrict__ x,
                           const float* __restrict__ lambdas,
                           float* __restrict__ ws_scale,
                           float* __restrict__ ws_val,
                           int* __restrict__ ws_cross) {
    int f = blockIdx.x * blockDim.x + threadIdx.x;
    if (f >= FEAT) return;
    float c = x[f];                 // generator 0 = center
    float r = 0.f;
    #pragma unroll 8
    for (int g = 1; g < G_GEN; ++g) r += fabsf(x[g * FEAT + f]);
    float l = c - r;
    float u = c + r;
    bool zero_m = (u <= 0.f);
    bool cross  = (!zero_m) && (l < 0.f);
    float d     = u - l;
    float denom = (d > 0.f) ? d : 1.f;
    float slope = u / denom;
    float lam   = lambdas[f];
    float val   = (lam >= slope) ? (-l * lam * 0.5f) : (u * (1.f - lam) * 0.5f);
    val = cross ? val : 0.f;
    float scale = zero_m ? 0.f : (cross ? lam : 1.f);
    ws_scale[f] = scale;
    ws_val[f]   = val;
    ws_cross[f] = cross ? 1 : 0;
}

// Kernel 2: single-block prefix scan of cross flags -> inverse rank mapping:
// colOfRank[k] = feature index of k-th crossing feature (-1 if k >= n_cross),
// valOfRank[k] = its val.
__global__ void scan_rankmap(const float* __restrict__ ws_val,
                             const int* __restrict__ ws_cross,
                             int* __restrict__ colOfRank,
                             float* __restrict__ valOfRank) {
    __shared__ int sums[256];
    const int t = threadIdx.x;
    const int PER = FEAT / 256;           // 32 features per thread, contiguous
    const int base = t * PER;
    int flags[PER];
    int local = 0;
    #pragma unroll
    for (int i = 0; i < PER; ++i) { flags[i] = ws_cross[base + i]; local += flags[i]; }
    sums[t] = local;
    __syncthreads();
    // Hillis-Steele inclusive scan over 256 thread-sums
    for (int off = 1; off < 256; off <<= 1) {
        int v   = sums[t];
        int add = (t >= off) ? sums[t - off] : 0;
        __syncthreads();
        sums[t] = v + add;
        __syncthreads();
    }
    int nc = sums[255];
    // init the tail (ranks with no crossing feature)
    for (int k = t; k < FEAT; k += 256) {
        if (k >= nc) { colOfRank[k] = -1; valOfRank[k] = 0.f; }
    }
    int rank = (t > 0) ? sums[t - 1] : 0;  // exclusive prefix for this thread's chunk
    #pragma unroll
    for (int i = 0; i < PER; ++i) {
        if (flags[i]) {
            colOfRank[rank] = base + i;
            valOfRank[rank] = ws_val[base + i];
            ++rank;
        }
    }
}

// Kernel 3: fused zero-fill + scatter for the eps block. One block per row
// (row k of the eps block = output row G_GEN+k). 256 threads x 8 float4 = 8192 floats.
__global__ void eps_fill(const int* __restrict__ colOfRank,
                         const float* __restrict__ valOfRank,
                         float* __restrict__ out) {
    const int row = blockIdx.x;           // 0..FEAT-1
    float* rowp = out + (size_t)(G_GEN + row) * FEAT;
    const int  colk = colOfRank[row];
    const float v   = valOfRank[row];
    const int t = threadIdx.x;
    #pragma unroll
    for (int i = 0; i < 8; ++i) {
        int c4 = t + i * 256;             // float4 index, coalesced across lanes
        f32x4 z = (f32x4)0.f;
        int cbase = c4 * 4;
        if (colk >= cbase && colk < cbase + 4) {
            z[colk - cbase] = v;
        }
        __builtin_nontemporal_store(z, reinterpret_cast<f32x4*>(rowp) + c4);
    }
}

// Kernel 4: base block out[g*FEAT+f] = x[g*FEAT+f]*scale[f] + (g==0)*val[f]
__global__ void write_base(const float* __restrict__ x,
                           const float* __restrict__ ws_scale,
                           const float* __restrict__ ws_val,
                           float* __restrict__ out) {
    int idx = blockIdx.x * blockDim.x + threadIdx.x;
    if (idx >= NBASE) return;
    int f = idx & (FEAT - 1);
    float v = x[idx] * ws_scale[f];
    if (idx < FEAT) v += ws_val[f];    // g == 0 row gets +val
    out[idx] = v;
}

extern "C" void kernel_launch(void* const* d_in, const int* in_sizes, int n_in,
                              void* d_out, int out_size, void* d_ws, size_t ws_size,
                              hipStream_t stream) {
    const float* x       = (const float*)d_in[0];
    const float* lambdas = (const float*)d_in[1];
    float* out = (float*)d_out;

    float* ws_scale   = (float*)d_ws;
    float* ws_val     = ws_scale + FEAT;
    int*   ws_cross   = (int*)(ws_val + FEAT);
    int*   colOfRank  = ws_cross + FEAT;
    float* valOfRank  = (float*)(colOfRank + FEAT);

    feat_stats<<<FEAT / 256, 256, 0, stream>>>(x, lambdas, ws_scale, ws_val, ws_cross);
    scan_rankmap<<<1, 256, 0, stream>>>(ws_val, ws_cross, colOfRank, valOfRank);
    eps_fill<<<FEAT, 256, 0, stream>>>(colOfRank, valOfRank, out);
    write_base<<<(NBASE + 255) / 256, 256, 0, stream>>>(x, ws_scale, ws_val, out);
}

// Round 4
// 62.881 us; speedup vs baseline: 1.3037x; 1.3037x over previous
//
#include <hip/hip_runtime.h>

#define G_GEN 65
#define FEAT 8192     // 32*16*16
#define NSTAT 32      // stats+base blocks (32*256 = 8192 features)
#define NFILL 2048    // eps zero-fill blocks

typedef float f32x4 __attribute__((ext_vector_type(4)));

// Kernel A: block-role split.
//  blocks [0,32):    per-feature stats (center/radius -> scale,val,cross) AND the
//                    65-row base block (runs concurrently with the fill blocks).
//  blocks [32,2080): zero-fill the 8192x8192 eps block with plain float4 stores.
__global__ void __launch_bounds__(256) fill_stats_base(
    const float* __restrict__ x, const float* __restrict__ lambdas,
    float* __restrict__ ws_val, int* __restrict__ ws_cross,
    float* __restrict__ out)
{
    const int bid = blockIdx.x;
    const int t = threadIdx.x;
    if (bid < NSTAT) {
        const int f = bid * 256 + t;          // coalesced across lanes
        float c = x[f];                       // generator 0 = center
        float r = 0.f;
        #pragma unroll 8
        for (int g = 1; g < G_GEN; ++g) r += fabsf(x[g * FEAT + f]);
        float l = c - r, u = c + r;
        bool zero_m = (u <= 0.f);
        bool cross  = (!zero_m) && (l < 0.f);
        float d     = u - l;
        float denom = (d > 0.f) ? d : 1.f;
        float slope = u / denom;
        float lam   = lambdas[f];
        float val   = (lam >= slope) ? (-l * lam * 0.5f) : (u * (1.f - lam) * 0.5f);
        val = cross ? val : 0.f;
        float scale = zero_m ? 0.f : (cross ? lam : 1.f);
        ws_val[f]   = val;
        ws_cross[f] = cross ? 1 : 0;
        // base block: out[g*FEAT+f] = x[g*FEAT+f]*scale + (g==0)*val
        out[f] = c * scale + val;             // g == 0 row
        #pragma unroll 8
        for (int g = 1; g < G_GEN; ++g)
            out[g * FEAT + f] = x[g * FEAT + f] * scale;  // x re-read hits L2
    } else {
        // zero-fill eps block: 8192*8192 floats = 16M float4, 2048 blocks x 256 thr x 32
        f32x4* eps = reinterpret_cast<f32x4*>(out + (size_t)G_GEN * FEAT);
        const size_t idx0   = (size_t)(bid - NSTAT) * 256 + t;
        const size_t stride = (size_t)NFILL * 256;
        f32x4 z = (f32x4)0.f;
        #pragma unroll
        for (int i = 0; i < 32; ++i)
            eps[idx0 + (size_t)i * stride] = z;   // plain stores (NT hurt in R3)
    }
}

// Kernel B: single-block prefix scan of cross flags (global cumsum order),
// then scatter val[f] into eps block at row (G_GEN + rank[f]), col f.
// (Verified correct in round 1.)
__global__ void scan_scatter(const float* __restrict__ ws_val,
                             const int* __restrict__ ws_cross,
                             float* __restrict__ out) {
    __shared__ int sums[256];
    const int t = threadIdx.x;
    const int PER = FEAT / 256;           // 32 features per thread, contiguous
    const int base = t * PER;
    int flags[PER];
    int local = 0;
    #pragma unroll
    for (int i = 0; i < PER; ++i) { flags[i] = ws_cross[base + i]; local += flags[i]; }
    sums[t] = local;
    __syncthreads();
    for (int off = 1; off < 256; off <<= 1) {
        int v   = sums[t];
        int add = (t >= off) ? sums[t - off] : 0;
        __syncthreads();
        sums[t] = v + add;
        __syncthreads();
    }
    int rank = (t > 0) ? sums[t - 1] : 0;  // exclusive prefix for this chunk
    #pragma unroll
    for (int i = 0; i < PER; ++i) {
        if (flags[i]) {
            out[(size_t)(G_GEN + rank) * FEAT + (base + i)] = ws_val[base + i];
            ++rank;
        }
    }
}

extern "C" void kernel_launch(void* const* d_in, const int* in_sizes, int n_in,
                              void* d_out, int out_size, void* d_ws, size_t ws_size,
                              hipStream_t stream) {
    const float* x       = (const float*)d_in[0];
    const float* lambdas = (const float*)d_in[1];
    float* out = (float*)d_out;

    float* ws_val   = (float*)d_ws;
    int*   ws_cross = (int*)(ws_val + FEAT);

    fill_stats_base<<<NSTAT + NFILL, 256, 0, stream>>>(x, lambdas, ws_val, ws_cross, out);
    scan_scatter<<<1, 256, 0, stream>>>(ws_val, ws_cross, out);
}

// Round 5
// 46.916 us; speedup vs baseline: 1.7473x; 1.3403x over previous
//
#include <hip/hip_runtime.h>

#define G_GEN 65
#define FEAT 8192     // 32*16*16
#define NSTAT 32      // stats+base blocks (32*256 = 8192 features)
#define NFILL 2048    // eps zero-fill blocks

typedef float f32x4 __attribute__((ext_vector_type(4)));
typedef int   i32x4 __attribute__((ext_vector_type(4)));

// Kernel A: block-role split.
//  blocks [0,32):    per-feature stats (center/radius -> scale,val,cross) AND the
//                    65-row base block (runs concurrently with the fill blocks).
//  blocks [32,2080): zero-fill the 8192x8192 eps block. Each block owns a
//                    CONTIGUOUS 128 KB chunk (32 iters x 256 lanes x 16 B),
//                    matching the rocclr memset access pattern.
__global__ void __launch_bounds__(256) fill_stats_base(
    const float* __restrict__ x, const float* __restrict__ lambdas,
    float* __restrict__ ws_val, int* __restrict__ ws_cross,
    float* __restrict__ out)
{
    const int bid = blockIdx.x;
    const int t = threadIdx.x;
    if (bid < NSTAT) {
        const int f = bid * 256 + t;          // coalesced across lanes
        float c = x[f];                       // generator 0 = center
        float r = 0.f;
        #pragma unroll 8
        for (int g = 1; g < G_GEN; ++g) r += fabsf(x[g * FEAT + f]);
        float l = c - r, u = c + r;
        bool zero_m = (u <= 0.f);
        bool cross  = (!zero_m) && (l < 0.f);
        float d     = u - l;
        float denom = (d > 0.f) ? d : 1.f;
        float slope = u / denom;
        float lam   = lambdas[f];
        float val   = (lam >= slope) ? (-l * lam * 0.5f) : (u * (1.f - lam) * 0.5f);
        val = cross ? val : 0.f;
        float scale = zero_m ? 0.f : (cross ? lam : 1.f);
        ws_val[f]   = val;
        ws_cross[f] = cross ? 1 : 0;
        // base block: out[g*FEAT+f] = x[g*FEAT+f]*scale + (g==0)*val
        out[f] = c * scale + val;             // g == 0 row
        #pragma unroll 8
        for (int g = 1; g < G_GEN; ++g)
            out[g * FEAT + f] = x[g * FEAT + f] * scale;  // x re-read hits L2
    } else {
        // zero-fill eps block: 16M float4 total; contiguous 8192-float4 chunk/block
        f32x4* eps = reinterpret_cast<f32x4*>(out + (size_t)G_GEN * FEAT);
        const size_t base = (size_t)(bid - NSTAT) * (256 * 32);
        f32x4 z = (f32x4)0.f;
        #pragma unroll
        for (int i = 0; i < 32; ++i)
            eps[base + (size_t)i * 256 + t] = z;
    }
}

// Kernel B: single-block (1024 threads) prefix scan of cross flags, then scatter
// val[f] into eps block at row (G_GEN + rank[f]), col f. 8 features/thread.
__global__ void __launch_bounds__(1024) scan_scatter(
    const float* __restrict__ ws_val,
    const int* __restrict__ ws_cross,
    float* __restrict__ out)
{
    __shared__ int sums[1024];
    const int t = threadIdx.x;
    const int base = t * 8;                   // 8 contiguous features per thread
    const i32x4* cp = reinterpret_cast<const i32x4*>(ws_cross + base);
    i32x4 c0 = cp[0], c1 = cp[1];
    int flags[8] = {c0[0], c0[1], c0[2], c0[3], c1[0], c1[1], c1[2], c1[3]};
    int local = 0;
    #pragma unroll
    for (int i = 0; i < 8; ++i) local += flags[i];
    sums[t] = local;
    __syncthreads();
    // Hillis-Steele inclusive scan over 1024 thread-sums
    for (int off = 1; off < 1024; off <<= 1) {
        int v   = sums[t];
        int add = (t >= off) ? sums[t - off] : 0;
        __syncthreads();
        sums[t] = v + add;
        __syncthreads();
    }
    int rank = (t > 0) ? sums[t - 1] : 0;     // exclusive prefix for this chunk
    const f32x4* vp = reinterpret_cast<const f32x4*>(ws_val + base);
    f32x4 v0 = vp[0], v1 = vp[1];
    float vals[8] = {v0[0], v0[1], v0[2], v0[3], v1[0], v1[1], v1[2], v1[3]};
    #pragma unroll
    for (int i = 0; i < 8; ++i) {
        if (flags[i]) {
            out[(size_t)(G_GEN + rank) * FEAT + (base + i)] = vals[i];
            ++rank;
        }
    }
}

extern "C" void kernel_launch(void* const* d_in, const int* in_sizes, int n_in,
                              void* d_out, int out_size, void* d_ws, size_t ws_size,
                              hipStream_t stream) {
    const float* x       = (const float*)d_in[0];
    const float* lambdas = (const float*)d_in[1];
    float* out = (float*)d_out;

    float* ws_val   = (float*)d_ws;
    int*   ws_cross = (int*)(ws_val + FEAT);

    fill_stats_base<<<NSTAT + NFILL, 256, 0, stream>>>(x, lambdas, ws_val, ws_cross, out);
    scan_scatter<<<1, 1024, 0, stream>>>(ws_val, ws_cross, out);
}